// Round 1
// baseline (44765.851 us; speedup 1.0000x reference)
//
#include <hip/hip_runtime.h>
#include <math.h>

// Problem constants
#define T_ENC 512
#define NB    128
#define LDEC  256
#define KVD   128
#define VSD   128
#define EMBD  256
#define HID   512
#define VOCD  34

// ---------------- workspace layout (floats) ----------------
// W1P   : [256 blocks][640 k][8 j]   = 1,310,720   (j = (u-2b)*4 + q, gate q in {i,f,g,o})
// EG    : [34 tok][2048 (u*4+q)]     =    69,632   (emb@Wih1_embpart + b_ih1 + b_hh1)
// W2P   : [64 blocks][640 k][8 j]    =   327,680
// B2    : [512 (u*4+q)]              =       512
// WoT   : [256 k][34 v]              =     8,704
// states: h1T x2, c1T (512x128); h2T x2, c2T, h2row, ctxT (128x128)
#define OFF_W1P   0
#define OFF_EG    1310720
#define OFF_W2P   1380352
#define OFF_B2    1708032
#define OFF_WOT   1708544
#define OFF_ST    1717248
// state sub-offsets (relative to OFF_ST)
#define ST_H1T0   0
#define ST_H1T1   65536
#define ST_C1T    131072
#define ST_H2T0   196608
#define ST_H2T1   212992
#define ST_C2T    229376
#define ST_H2ROW  245760
#define ST_CTXT   262144
#define ST_SIZE   278528

__device__ __forceinline__ float sigf(float x) { return 1.0f / (1.0f + expf(-x)); }

// ---- pack kernels (run every launch; deterministic) ----
__global__ __launch_bounds__(256) void pack_w1(const float* __restrict__ Wih1,
                                               const float* __restrict__ Whh1,
                                               float* __restrict__ W1P) {
  int idx = blockIdx.x * 256 + threadIdx.x;   // < 1,310,720
  int b = idx / 5120, r = idx % 5120;
  int k = r >> 3, j = r & 7;
  int q = j & 3, u = 2 * b + (j >> 2);
  int g = q * 512 + u;                        // original gate row (i,f,g,o chunks of 512)
  float v = (k < 128) ? Wih1[g * 384 + 256 + k]      // ctx part of x
                      : Whh1[g * 512 + (k - 128)];   // h1 recurrent part
  W1P[idx] = v;
}

__global__ __launch_bounds__(256) void pack_eg(const float* __restrict__ emb,
                                               const float* __restrict__ Wih1,
                                               const float* __restrict__ bih1,
                                               const float* __restrict__ bhh1,
                                               float* __restrict__ EG) {
  int idx = blockIdx.x * 256 + threadIdx.x;   // < 69,632
  int v = idx / 2048, gl = idx % 2048;
  int u = gl >> 2, q = gl & 3;
  int g = q * 512 + u;
  float acc = bih1[g] + bhh1[g];
  const float* e = emb + v * 256;
  const float* w = Wih1 + g * 384;
  for (int k = 0; k < 256; k++) acc += e[k] * w[k];
  EG[idx] = acc;
}

__global__ __launch_bounds__(256) void pack_w2(const float* __restrict__ Wih2,
                                               const float* __restrict__ Whh2,
                                               float* __restrict__ W2P) {
  int idx = blockIdx.x * 256 + threadIdx.x;   // < 327,680
  int b = idx / 5120, r = idx % 5120;
  int k = r >> 3, j = r & 7;
  int q = j & 3, u = 2 * b + (j >> 2);
  int g = q * 128 + u;
  W2P[idx] = (k < 512) ? Wih2[g * 512 + k] : Whh2[g * 128 + (k - 512)];
}

__global__ __launch_bounds__(256) void pack_misc(const float* __restrict__ Wout,
                                                 const float* __restrict__ bih2,
                                                 const float* __restrict__ bhh2,
                                                 float* __restrict__ WoT,
                                                 float* __restrict__ B2) {
  int idx = blockIdx.x * 256 + threadIdx.x;
  if (idx < 8704) {
    int k = idx / 34, v = idx % 34;
    WoT[idx] = Wout[v * 256 + k];
  } else if (idx < 9216) {
    int j = idx - 8704;
    int u = j >> 2, q = j & 3;
    int g = q * 128 + u;
    B2[j] = bih2[g] + bhh2[g];
  }
}

// ---- phase A: gates1 GEMM + LSTM1 pointwise. 256 blocks, block b owns units 2b,2b+1 ----
__global__ __launch_bounds__(256) void phaseA(const float* __restrict__ W1P,
                                              const float* __restrict__ EG,
                                              const int* __restrict__ text,
                                              const float* __restrict__ ctxT,
                                              const float* __restrict__ h1T_old,
                                              float* __restrict__ h1T_new,
                                              float* __restrict__ c1T, int t) {
  __shared__ float4 wsv[1280];                // 640 k x 2 halves (each float4 = 4 gates)
  int b = blockIdx.x, tid = threadIdx.x;
  int n = tid & 127, half = tid >> 7;
  const float4* Wp = (const float4*)W1P + b * 1280;
  for (int i = tid; i < 1280; i += 256) wsv[i] = Wp[i];
  __syncthreads();
  int u = 2 * b + half;
  int tok = text[n * LDEC + t];
  const float* eg = EG + tok * 2048 + u * 4;
  float a0 = eg[0], a1 = eg[1], a2 = eg[2], a3 = eg[3];
#pragma unroll 4
  for (int k = 0; k < 128; k++) {            // ctx part
    float xv = ctxT[k * 128 + n];
    float4 w = wsv[k * 2 + half];
    a0 += xv * w.x; a1 += xv * w.y; a2 += xv * w.z; a3 += xv * w.w;
  }
#pragma unroll 4
  for (int k = 0; k < 512; k++) {            // h1 recurrent part
    float xv = h1T_old[k * 128 + n];
    float4 w = wsv[(128 + k) * 2 + half];
    a0 += xv * w.x; a1 += xv * w.y; a2 += xv * w.z; a3 += xv * w.w;
  }
  float ig = sigf(a0), fg = sigf(a1), gg = tanhf(a2), og = sigf(a3);
  float c = fg * c1T[u * 128 + n] + ig * gg;
  float h = og * tanhf(c);
  c1T[u * 128 + n] = c;
  h1T_new[u * 128 + n] = h;
}

// ---- phase B: gates2 GEMM + LSTM2 pointwise. 64 blocks ----
__global__ __launch_bounds__(256) void phaseB(const float* __restrict__ W2P,
                                              const float* __restrict__ B2,
                                              const float* __restrict__ h1T,
                                              const float* __restrict__ h2T_old,
                                              float* __restrict__ h2T_new,
                                              float* __restrict__ c2T,
                                              float* __restrict__ h2row) {
  __shared__ float4 wsv[1280];
  int b = blockIdx.x, tid = threadIdx.x;
  int n = tid & 127, half = tid >> 7;
  const float4* Wp = (const float4*)W2P + b * 1280;
  for (int i = tid; i < 1280; i += 256) wsv[i] = Wp[i];
  __syncthreads();
  int u = 2 * b + half;
  const float* bb = B2 + u * 4;
  float a0 = bb[0], a1 = bb[1], a2 = bb[2], a3 = bb[3];
#pragma unroll 4
  for (int k = 0; k < 512; k++) {            // h1 input part
    float xv = h1T[k * 128 + n];
    float4 w = wsv[k * 2 + half];
    a0 += xv * w.x; a1 += xv * w.y; a2 += xv * w.z; a3 += xv * w.w;
  }
#pragma unroll 4
  for (int k = 0; k < 128; k++) {            // h2 recurrent part
    float xv = h2T_old[k * 128 + n];
    float4 w = wsv[(512 + k) * 2 + half];
    a0 += xv * w.x; a1 += xv * w.y; a2 += xv * w.z; a3 += xv * w.w;
  }
  float ig = sigf(a0), fg = sigf(a1), gg = tanhf(a2), og = sigf(a3);
  float c = fg * c2T[u * 128 + n] + ig * gg;
  float h = og * tanhf(c);
  c2T[u * 128 + n] = c;
  h2T_new[u * 128 + n] = h;
  h2row[n * 128 + u] = h;
}

// ---- phase C: masked attention + output projection. 128 blocks (one per batch n) ----
__global__ __launch_bounds__(256) void phaseC(const float* __restrict__ key,
                                              const float* __restrict__ values,
                                              const int* __restrict__ lens,
                                              const float* __restrict__ h2row,
                                              const float* __restrict__ WoT,
                                              const float* __restrict__ bout,
                                              float* __restrict__ ctxT,
                                              float* __restrict__ out, int t) {
  __shared__ float h2s[128];
  __shared__ float es[512];
  __shared__ float red[256];
  __shared__ float ctxs[128];
  __shared__ float pr[68];
  int n = blockIdx.x, tid = threadIdx.x;
  int len = lens[n];
  if (tid < 128) h2s[tid] = h2row[n * 128 + tid];
  __syncthreads();
  // energy over valid t only (mask -1e9 == skip: softmax identical)
  float lmax = -1e30f;
  for (int tt = tid; tt < len; tt += 256) {
    const float4* kr = (const float4*)(key + ((size_t)tt * 128 + n) * 128);
    float acc = 0.0f;
#pragma unroll 8
    for (int k = 0; k < 32; k++) {
      float4 kv = kr[k];
      acc += kv.x * h2s[4 * k] + kv.y * h2s[4 * k + 1] + kv.z * h2s[4 * k + 2] + kv.w * h2s[4 * k + 3];
    }
    es[tt] = acc;
    lmax = fmaxf(lmax, acc);
  }
  red[tid] = lmax; __syncthreads();
  for (int s = 128; s > 0; s >>= 1) { if (tid < s) red[tid] = fmaxf(red[tid], red[tid + s]); __syncthreads(); }
  float m = red[0];
  __syncthreads();
  float lsum = 0.0f;
  for (int tt = tid; tt < len; tt += 256) {
    float p = expf(es[tt] - m);
    es[tt] = p;
    lsum += p;
  }
  red[tid] = lsum; __syncthreads();
  for (int s = 128; s > 0; s >>= 1) { if (tid < s) red[tid] += red[tid + s]; __syncthreads(); }
  float S = red[0];
  __syncthreads();
  // ctx = attn @ values
  int v = tid & 127, tpar = tid >> 7;
  float acc = 0.0f;
  for (int tt = tpar; tt < len; tt += 2) {
    acc += es[tt] * values[((size_t)tt * 128 + n) * 128 + v];
  }
  red[tid] = acc; __syncthreads();
  if (tid < 128) {
    float cv = (red[tid] + red[tid + 128]) / S;
    ctxs[tid] = cv;
    ctxT[tid * 128 + n] = cv;             // transposed store for next step's phase A
  }
  __syncthreads();
  // pred = [h2, ctx] @ W_out^T + b_out
  if (tid < 68) {
    int vv = tid % 34, part = tid / 34;
    const float* src = part ? ctxs : h2s;
    const float* wcol = WoT + (part ? 128 * 34 : 0);
    float a = 0.0f;
    for (int k = 0; k < 128; k++) a += src[k] * wcol[k * 34 + vv];
    pr[tid] = a;
  }
  __syncthreads();
  if (tid < 34) {
    out[(size_t)n * (LDEC * VOCD) + t * VOCD + tid] = bout[tid] + pr[tid] + pr[34 + tid];
  }
}

extern "C" void kernel_launch(void* const* d_in, const int* in_sizes, int n_in,
                              void* d_out, int out_size, void* d_ws, size_t ws_size,
                              hipStream_t stream) {
  const float* key    = (const float*)d_in[0];
  const float* values = (const float*)d_in[1];
  const int*   lens   = (const int*)d_in[2];
  const int*   text   = (const int*)d_in[3];
  const float* emb    = (const float*)d_in[4];
  const float* Wih1   = (const float*)d_in[5];
  const float* Whh1   = (const float*)d_in[6];
  const float* bih1   = (const float*)d_in[7];
  const float* bhh1   = (const float*)d_in[8];
  const float* Wih2   = (const float*)d_in[9];
  const float* Whh2   = (const float*)d_in[10];
  const float* bih2   = (const float*)d_in[11];
  const float* bhh2   = (const float*)d_in[12];
  const float* Wout   = (const float*)d_in[13];
  const float* bout   = (const float*)d_in[14];

  float* ws   = (float*)d_ws;
  float* W1P  = ws + OFF_W1P;
  float* EG   = ws + OFF_EG;
  float* W2P  = ws + OFF_W2P;
  float* B2   = ws + OFF_B2;
  float* WoT  = ws + OFF_WOT;
  float* st   = ws + OFF_ST;
  float* h1T0 = st + ST_H1T0;
  float* h1T1 = st + ST_H1T1;
  float* c1T  = st + ST_C1T;
  float* h2T0 = st + ST_H2T0;
  float* h2T1 = st + ST_H2T1;
  float* c2T  = st + ST_C2T;
  float* h2row= st + ST_H2ROW;
  float* ctxT = st + ST_CTXT;
  float* out  = (float*)d_out;

  // zero all recurrent state (ws is poisoned 0xAA; must re-init every call)
  hipMemsetAsync(st, 0, (size_t)ST_SIZE * sizeof(float), stream);

  pack_w1  <<<5120, 256, 0, stream>>>(Wih1, Whh1, W1P);
  pack_eg  <<<272,  256, 0, stream>>>(emb, Wih1, bih1, bhh1, EG);
  pack_w2  <<<1280, 256, 0, stream>>>(Wih2, Whh2, W2P);
  pack_misc<<<36,   256, 0, stream>>>(Wout, bih2, bhh2, WoT, B2);

  for (int t = 0; t < LDEC; t++) {
    float* h1_old = (t & 1) ? h1T1 : h1T0;
    float* h1_new = (t & 1) ? h1T0 : h1T1;
    float* h2_old = (t & 1) ? h2T1 : h2T0;
    float* h2_new = (t & 1) ? h2T0 : h2T1;
    phaseA<<<256, 256, 0, stream>>>(W1P, EG, text, ctxT, h1_old, h1_new, c1T, t);
    phaseB<<<64,  256, 0, stream>>>(W2P, B2, h1_new, h2_old, h2_new, c2T, h2row);
    phaseC<<<128, 256, 0, stream>>>(key, values, lens, h2row, WoT, bout, ctxT, out, t);
  }
}